// Round 2
// baseline (1542.894 us; speedup 1.0000x reference)
//
#include <hip/hip_runtime.h>

#define WG 256

// ---------------- setup kernels ----------------

__global__ void k_zero2(int* __restrict__ a, int* __restrict__ b, int n) {
    int i = blockIdx.x * blockDim.x + threadIdx.x;
    if (i < n) { a[i] = 0; b[i] = 0; }
}

__global__ void k_count(const int* __restrict__ dst, int* __restrict__ deg, int E) {
    int e = blockIdx.x * blockDim.x + threadIdx.x;
    if (e < E) atomicAdd(&deg[dst[e]], 1);
}

__global__ void k_dis(const int* __restrict__ deg, float* __restrict__ dis, int N) {
    int n = blockIdx.x * blockDim.x + threadIdx.x;
    if (n < N) {
        int d = deg[n];
        dis[n] = (d > 0) ? rsqrtf((float)d) : 0.0f;
    }
}

// single-block exclusive scan of deg -> rowptr[0..N]
__global__ __launch_bounds__(1024) void k_scan(const int* __restrict__ deg,
                                               int* __restrict__ rowptr, int N) {
    __shared__ int sums[1024];
    int t = threadIdx.x;
    int chunk = (N + 1023) / 1024;
    int start = t * chunk;
    int end = start + chunk; if (end > N) end = N;
    int s = 0;
    for (int i = start; i < end; ++i) s += deg[i];
    sums[t] = s;
    __syncthreads();
    for (int off = 1; off < 1024; off <<= 1) {
        int v = (t >= off) ? sums[t - off] : 0;
        __syncthreads();
        sums[t] += v;
        __syncthreads();
    }
    int run = sums[t] - s;   // exclusive prefix
    for (int i = start; i < end; ++i) { rowptr[i] = run; run += deg[i]; }
    if (start < N && end == N) rowptr[N] = run;
}

__global__ void k_scatter(const int* __restrict__ src, const int* __restrict__ dst,
                          const int* __restrict__ rowptr, int* __restrict__ fill,
                          const float* __restrict__ dis,
                          int* __restrict__ csrc, float* __restrict__ cw, int E) {
    int e = blockIdx.x * blockDim.x + threadIdx.x;
    if (e >= E) return;
    int d = dst[e], s = src[e];
    int slot = rowptr[d] + atomicAdd(&fill[d], 1);
    csrc[slot] = s;
    cw[slot] = dis[s] * dis[d];
}

// X (B,WIN,N) f32 -> h0 [n][b][w] f32   (B=4, WIN=5)
__global__ void k_xpose(const float* __restrict__ X, float* __restrict__ h0, int N) {
    int tid = blockIdx.x * blockDim.x + threadIdx.x;
    if (tid >= N * 20) return;
    int n = tid / 20, r = tid % 20;
    int b = r / 5, w = r % 5;
    h0[tid] = X[(b * 5 + w) * N + n];
}

// ---------------- propagation: out[n][c] = sum_j w[j] * in[src_j][c] ----------------
template <int C>
__global__ void k_spmm(const int* __restrict__ rowptr, const int* __restrict__ csrc,
                       const float* __restrict__ cw, const float* __restrict__ hin,
                       float* __restrict__ hout, int N) {
    int tid = blockIdx.x * blockDim.x + threadIdx.x;
    int n = tid / C, c = tid % C;
    if (n >= N) return;
    float acc = 0.0f;
    int j0 = rowptr[n], j1 = rowptr[n + 1];
    for (int j = j0; j < j1; ++j)
        acc += cw[j] * hin[csrc[j] * C + c];
    hout[tid] = acc;
}

// acc[n][b][o] (+)= sum_f h[n][b][f] * W[f][o]   (W is one k-slice, f32, F x 32)
template <int F>
__global__ void k_matmul_acc(const float* __restrict__ h, const float* __restrict__ W,
                             float* __restrict__ acc, int N, int first) {
    __shared__ float w[F * 32];
    int t = threadIdx.x;
    for (int i = t; i < F * 32; i += WG) w[i] = W[i];
    __syncthreads();
    int tid = blockIdx.x * WG + t;
    int node = tid >> 7;
    if (node >= N) return;
    int b = (tid >> 5) & 3, o = tid & 31;
    const float* hp = h + (node * 4 + b) * F;
    float a = first ? 0.0f : acc[tid];
#pragma unroll
    for (int f = 0; f < F; ++f) a += hp[f] * w[f * 32 + o];
    acc[tid] = a;
}

// h_new = tanh(acc + bias); optionally also write h to d_out region, layout (b*N+n)*32+o
__global__ void k_tanh_bias(const float* __restrict__ acc, const float* __restrict__ bias,
                            float* __restrict__ hout, float* hout_final, int N) {
    int tid = blockIdx.x * blockDim.x + threadIdx.x;
    if (tid >= N * 128) return;
    int o = tid & 31;
    float v = tanhf(acc[tid] + bias[o]);
    hout[tid] = v;
    if (hout_final) {
        int node = tid >> 7, b = (tid >> 5) & 3;
        hout_final[((size_t)(b * N + node)) * 32 + o] = v;
    }
}

// pred[b*N+n] = sum_o h[n][b][o]*Wr[o] + br
__global__ void k_pred(const float* __restrict__ h, const float* __restrict__ Wr,
                       const float* __restrict__ br, float* __restrict__ out, int N) {
    int tid = blockIdx.x * blockDim.x + threadIdx.x;
    if (tid >= 4 * N) return;
    int b = tid / N, n = tid % N;
    const float* hp = h + (n * 4 + b) * 32;
    float a = br[0];
#pragma unroll
    for (int o = 0; o < 32; ++o) a += hp[o] * Wr[o];
    out[b * N + n] = a;
}

// ---------------- driver ----------------

extern "C" void kernel_launch(void* const* d_in, const int* in_sizes, int n_in,
                              void* d_out, int out_size, void* d_ws, size_t ws_size,
                              hipStream_t stream) {
    const float* X  = (const float*)d_in[0];
    const int*   ei = (const int*)d_in[1];
    const float* W0 = (const float*)d_in[2];
    const float* b0 = (const float*)d_in[3];
    const float* W1 = (const float*)d_in[4];
    const float* b1 = (const float*)d_in[5];
    const float* W2 = (const float*)d_in[6];
    const float* b2 = (const float*)d_in[7];
    const float* Wr = (const float*)d_in[8];
    const float* br = (const float*)d_in[9];

    const int N = in_sizes[0] / 20;   // B*WIN = 20
    const int E = in_sizes[1] / 2;
    const int* src = ei;
    const int* dst = ei + E;

    char* ws = (char*)d_ws;
    size_t off = 0;
    auto take = [&](size_t bytes) -> char* {
        char* p = ws + off;
        off = (off + bytes + 255) & ~(size_t)255;
        return p;
    };
    int*   deg    = (int*)  take((size_t)N * 4);
    int*   fill   = (int*)  take((size_t)N * 4);
    int*   rowptr = (int*)  take(((size_t)N + 1) * 4);
    float* dis    = (float*)take((size_t)N * 4);
    int*   csrc   = (int*)  take((size_t)E * 4);
    float* cw     = (float*)take((size_t)E * 4);
    float* bufA   = (float*)take((size_t)N * 128 * 4);
    float* bufB   = (float*)take((size_t)N * 128 * 4);
    float* bufC   = (float*)take((size_t)N * 128 * 4);
    if (ws_size < off) return;  // insufficient scratch -> outputs stay zero (visible failure)

    dim3 wg(WG);
    auto nb = [](long long total) { return dim3((unsigned)((total + WG - 1) / WG)); };

    // ---- graph/normalization setup ----
    k_zero2<<<nb(N), wg, 0, stream>>>(deg, fill, N);
    k_count<<<nb(E), wg, 0, stream>>>(dst, deg, E);
    k_dis<<<nb(N), wg, 0, stream>>>(deg, dis, N);
    k_scan<<<1, 1024, 0, stream>>>(deg, rowptr, N);
    k_scatter<<<nb(E), wg, 0, stream>>>(src, dst, rowptr, fill, dis, csrc, cw, E);

    // ---- h0 = X^T, layout [n][b][w], f32 ----
    k_xpose<<<nb((long long)N * 20), wg, 0, stream>>>(X, bufA, N);

    float* out_pred = (float*)d_out;
    float* out_h    = (float*)d_out + (size_t)4 * N;

    // ---- layer 0: F=5 -> 32 ----
    {
        float* hcur = bufA; float* hnext = bufB;
        k_matmul_acc<5><<<nb((long long)N * 128), wg, 0, stream>>>(hcur, W0, bufC, N, 1);
        for (int k = 1; k <= 3; ++k) {
            k_spmm<20><<<nb((long long)N * 20), wg, 0, stream>>>(rowptr, csrc, cw, hcur, hnext, N);
            k_matmul_acc<5><<<nb((long long)N * 128), wg, 0, stream>>>(hnext, W0 + k * 5 * 32, bufC, N, 0);
            float* tmp = hcur; hcur = hnext; hnext = tmp;
        }
        k_tanh_bias<<<nb((long long)N * 128), wg, 0, stream>>>(bufC, b0, bufA, nullptr, N);
    }

    // ---- layers 1 and 2: F=32 -> 32 ----
    for (int layer = 1; layer <= 2; ++layer) {
        const float* W = (layer == 1) ? W1 : W2;
        const float* bb = (layer == 1) ? b1 : b2;
        float* hcur = bufA; float* hnext = bufB;
        k_matmul_acc<32><<<nb((long long)N * 128), wg, 0, stream>>>(hcur, W, bufC, N, 1);
        for (int k = 1; k <= 3; ++k) {
            k_spmm<128><<<nb((long long)N * 128), wg, 0, stream>>>(rowptr, csrc, cw, hcur, hnext, N);
            k_matmul_acc<32><<<nb((long long)N * 128), wg, 0, stream>>>(hnext, W + k * 32 * 32, bufC, N, 0);
            float* tmp = hcur; hcur = hnext; hnext = tmp;
        }
        k_tanh_bias<<<nb((long long)N * 128), wg, 0, stream>>>(bufC, bb, bufA,
                                                               (layer == 2) ? out_h : nullptr, N);
    }

    // ---- predictions ----
    k_pred<<<nb((long long)4 * N), wg, 0, stream>>>(bufA, Wr, br, out_pred, N);
}

// Round 3
// 805.947 us; speedup vs baseline: 1.9144x; 1.9144x over previous
//
#include <hip/hip_runtime.h>

#define WG 256

// ---------------- setup kernels ----------------

__global__ void k_zero2(int* __restrict__ a, int* __restrict__ b, int n) {
    int i = blockIdx.x * blockDim.x + threadIdx.x;
    if (i < n) { a[i] = 0; b[i] = 0; }
}

__global__ void k_count(const int* __restrict__ dst, int* __restrict__ deg, int E) {
    int e = blockIdx.x * blockDim.x + threadIdx.x;
    if (e < E) atomicAdd(&deg[dst[e]], 1);
}

__global__ void k_dis(const int* __restrict__ deg, float* __restrict__ dis, int N) {
    int n = blockIdx.x * blockDim.x + threadIdx.x;
    if (n < N) {
        int d = deg[n];
        dis[n] = (d > 0) ? rsqrtf((float)d) : 0.0f;
    }
}

// single-block exclusive scan of deg -> rowptr[0..N]
__global__ __launch_bounds__(1024) void k_scan(const int* __restrict__ deg,
                                               int* __restrict__ rowptr, int N) {
    __shared__ int sums[1024];
    int t = threadIdx.x;
    int chunk = (N + 1023) / 1024;
    int start = t * chunk;
    int end = start + chunk; if (end > N) end = N;
    int s = 0;
    for (int i = start; i < end; ++i) s += deg[i];
    sums[t] = s;
    __syncthreads();
    for (int off = 1; off < 1024; off <<= 1) {
        int v = (t >= off) ? sums[t - off] : 0;
        __syncthreads();
        sums[t] += v;
        __syncthreads();
    }
    int run = sums[t] - s;   // exclusive prefix
    for (int i = start; i < end; ++i) { rowptr[i] = run; run += deg[i]; }
    if (start < N && end == N) rowptr[N] = run;
}

// emeta[slot] = (src, w) packed as int2
__global__ void k_scatter(const int* __restrict__ src, const int* __restrict__ dst,
                          const int* __restrict__ rowptr, int* __restrict__ fill,
                          const float* __restrict__ dis,
                          int2* __restrict__ emeta, int E) {
    int e = blockIdx.x * blockDim.x + threadIdx.x;
    if (e >= E) return;
    int d = dst[e], s = src[e];
    int slot = rowptr[d] + atomicAdd(&fill[d], 1);
    emeta[slot] = make_int2(s, __float_as_int(dis[s] * dis[d]));
}

// X (B,WIN,N) f32 -> h0 [n][b][w] f32   (B=4, WIN=5)
__global__ void k_xpose(const float* __restrict__ X, float* __restrict__ h0, int N) {
    int tid = blockIdx.x * blockDim.x + threadIdx.x;
    if (tid >= N * 20) return;
    int n = tid / 20, r = tid % 20;
    int b = r / 5, w = r % 5;
    h0[tid] = X[(b * 5 + w) * N + n];
}

// ---------------- layer-0 propagation (C=20, scalar) ----------------
template <int C>
__global__ void k_spmm(const int* __restrict__ rowptr, const int2* __restrict__ emeta,
                       const float* __restrict__ hin, float* __restrict__ hout, int N) {
    int tid = blockIdx.x * blockDim.x + threadIdx.x;
    int n = tid / C, c = tid % C;
    if (n >= N) return;
    float acc = 0.0f;
    int j0 = rowptr[n], j1 = rowptr[n + 1];
    for (int j = j0; j < j1; ++j) {
        int2 m = emeta[j];
        acc += __int_as_float(m.y) * hin[(size_t)m.x * C + c];
    }
    hout[tid] = acc;
}

// ---------------- fused hop (F=32): hnext = A*hin ; acc += hnext * Wk ----------------
// 256 threads = 8 nodes x 32 lanes. Each lane owns 4 consecutive channels.
template <bool WRITE_H>
__global__ __launch_bounds__(256) void k_hop_fused(const int* __restrict__ rowptr,
                                                   const int2* __restrict__ emeta,
                                                   const float* __restrict__ hin,
                                                   float* __restrict__ hnext,
                                                   const float* __restrict__ Wk,   // 32x32 k-slice
                                                   float* __restrict__ acc, int N) {
    __shared__ float4 ws4[256];          // W staged, float4 of 4 consecutive outputs
    __shared__ float  hs[8 * 132];       // padded [8 nodes][4 b][33] -> conflict-free

    int t = threadIdx.x;
    ws4[t] = ((const float4*)Wk)[t];

    int nl = t >> 5, lane = t & 31;
    int n = blockIdx.x * 8 + nl;
    bool valid = (n < N);

    float ax = 0.f, ay = 0.f, az = 0.f, aw = 0.f;
    float bx = 0.f, by = 0.f, bz = 0.f, bw = 0.f;
    const float4* hin4 = (const float4*)hin;

    if (valid) {
        int j = rowptr[n], j1 = rowptr[n + 1];
        for (; j + 3 < j1; j += 4) {
            int2 m0 = emeta[j], m1 = emeta[j + 1], m2 = emeta[j + 2], m3 = emeta[j + 3];
            float4 g0 = hin4[(size_t)m0.x * 32 + lane];
            float4 g1 = hin4[(size_t)m1.x * 32 + lane];
            float4 g2 = hin4[(size_t)m2.x * 32 + lane];
            float4 g3 = hin4[(size_t)m3.x * 32 + lane];
            float w0 = __int_as_float(m0.y), w1 = __int_as_float(m1.y);
            float w2 = __int_as_float(m2.y), w3 = __int_as_float(m3.y);
            ax += w0 * g0.x; ay += w0 * g0.y; az += w0 * g0.z; aw += w0 * g0.w;
            bx += w1 * g1.x; by += w1 * g1.y; bz += w1 * g1.z; bw += w1 * g1.w;
            ax += w2 * g2.x; ay += w2 * g2.y; az += w2 * g2.z; aw += w2 * g2.w;
            bx += w3 * g3.x; by += w3 * g3.y; bz += w3 * g3.z; bw += w3 * g3.w;
        }
        for (; j < j1; ++j) {
            int2 m = emeta[j];
            float4 g = hin4[(size_t)m.x * 32 + lane];
            float w = __int_as_float(m.y);
            ax += w * g.x; ay += w * g.y; az += w * g.z; aw += w * g.w;
        }
        ax += bx; ay += by; az += bz; aw += bw;
        if (WRITE_H) {
            float4 o; o.x = ax; o.y = ay; o.z = az; o.w = aw;
            ((float4*)hnext)[(size_t)n * 32 + lane] = o;
        }
    }

    // stage hop result: lane -> b = lane>>3, f0 = (lane&7)*4
    int b = lane >> 3, q = lane & 7;
    float* hrow = &hs[nl * 132 + b * 33 + q * 4];
    hrow[0] = ax; hrow[1] = ay; hrow[2] = az; hrow[3] = aw;
    __syncthreads();
    if (!valid) return;

    // out[n][b][o0..o0+3] += sum_f h[n][b][f] * W[f][o0..]
    float rx = 0.f, ry = 0.f, rz = 0.f, rw = 0.f;
    const float* hb = &hs[nl * 132 + b * 33];
#pragma unroll
    for (int f = 0; f < 32; ++f) {
        float hv = hb[f];
        float4 wv = ws4[f * 8 + q];
        rx += hv * wv.x; ry += hv * wv.y; rz += hv * wv.z; rw += hv * wv.w;
    }
    float4* accp = (float4*)acc + (size_t)n * 32 + lane;
    float4 cur = *accp;
    cur.x += rx; cur.y += ry; cur.z += rz; cur.w += rw;
    *accp = cur;
}

// acc[n][b][o] (+)= sum_f h[n][b][f] * W[f][o]   (k=0 slices)
template <int F>
__global__ void k_matmul_acc(const float* __restrict__ h, const float* __restrict__ W,
                             float* __restrict__ acc, int N, int first) {
    __shared__ float w[F * 32];
    int t = threadIdx.x;
    for (int i = t; i < F * 32; i += WG) w[i] = W[i];
    __syncthreads();
    int tid = blockIdx.x * WG + t;
    int node = tid >> 7;
    if (node >= N) return;
    int b = (tid >> 5) & 3, o = tid & 31;
    const float* hp = h + (node * 4 + b) * F;
    float a = first ? 0.0f : acc[tid];
#pragma unroll
    for (int f = 0; f < F; ++f) a += hp[f] * w[f * 32 + o];
    acc[tid] = a;
}

// h_new = tanh(acc + bias); optionally also write h to d_out region, layout (b*N+n)*32+o
__global__ void k_tanh_bias(const float* __restrict__ acc, const float* __restrict__ bias,
                            float* __restrict__ hout, float* hout_final, int N) {
    int tid = blockIdx.x * blockDim.x + threadIdx.x;
    if (tid >= N * 128) return;
    int o = tid & 31;
    float v = tanhf(acc[tid] + bias[o]);
    hout[tid] = v;
    if (hout_final) {
        int node = tid >> 7, b = (tid >> 5) & 3;
        hout_final[((size_t)(b * N + node)) * 32 + o] = v;
    }
}

// pred[b*N+n] = sum_o h[n][b][o]*Wr[o] + br
__global__ void k_pred(const float* __restrict__ h, const float* __restrict__ Wr,
                       const float* __restrict__ br, float* __restrict__ out, int N) {
    int tid = blockIdx.x * blockDim.x + threadIdx.x;
    if (tid >= 4 * N) return;
    int b = tid / N, n = tid % N;
    const float* hp = h + (n * 4 + b) * 32;
    float a = br[0];
#pragma unroll
    for (int o = 0; o < 32; ++o) a += hp[o] * Wr[o];
    out[b * N + n] = a;
}

// ---------------- driver ----------------

extern "C" void kernel_launch(void* const* d_in, const int* in_sizes, int n_in,
                              void* d_out, int out_size, void* d_ws, size_t ws_size,
                              hipStream_t stream) {
    const float* X  = (const float*)d_in[0];
    const int*   ei = (const int*)d_in[1];
    const float* W0 = (const float*)d_in[2];
    const float* b0 = (const float*)d_in[3];
    const float* W1 = (const float*)d_in[4];
    const float* b1 = (const float*)d_in[5];
    const float* W2 = (const float*)d_in[6];
    const float* b2 = (const float*)d_in[7];
    const float* Wr = (const float*)d_in[8];
    const float* br = (const float*)d_in[9];

    const int N = in_sizes[0] / 20;   // B*WIN = 20
    const int E = in_sizes[1] / 2;
    const int* src = ei;
    const int* dst = ei + E;

    char* ws = (char*)d_ws;
    size_t off = 0;
    auto take = [&](size_t bytes) -> char* {
        char* p = ws + off;
        off = (off + bytes + 255) & ~(size_t)255;
        return p;
    };
    int*   deg    = (int*)  take((size_t)N * 4);
    int*   fill   = (int*)  take((size_t)N * 4);
    int*   rowptr = (int*)  take(((size_t)N + 1) * 4);
    float* dis    = (float*)take((size_t)N * 4);
    int2*  emeta  = (int2*) take((size_t)E * 8);
    float* bufA   = (float*)take((size_t)N * 128 * 4);
    float* bufB   = (float*)take((size_t)N * 128 * 4);
    float* bufC   = (float*)take((size_t)N * 128 * 4);
    if (ws_size < off) return;  // insufficient scratch -> outputs stay zero (visible failure)

    dim3 wg(WG);
    auto nb = [](long long total) { return dim3((unsigned)((total + WG - 1) / WG)); };

    // ---- graph/normalization setup ----
    k_zero2<<<nb(N), wg, 0, stream>>>(deg, fill, N);
    k_count<<<nb(E), wg, 0, stream>>>(dst, deg, E);
    k_dis<<<nb(N), wg, 0, stream>>>(deg, dis, N);
    k_scan<<<1, 1024, 0, stream>>>(deg, rowptr, N);
    k_scatter<<<nb(E), wg, 0, stream>>>(src, dst, rowptr, fill, dis, emeta, E);

    // ---- h0 = X^T, layout [n][b][w], f32 ----
    k_xpose<<<nb((long long)N * 20), wg, 0, stream>>>(X, bufA, N);

    float* out_pred = (float*)d_out;
    float* out_h    = (float*)d_out + (size_t)4 * N;

    // ---- layer 0: F=5 -> 32 (scalar path, small) ----
    {
        float* hcur = bufA; float* hnext = bufB;
        k_matmul_acc<5><<<nb((long long)N * 128), wg, 0, stream>>>(hcur, W0, bufC, N, 1);
        for (int k = 1; k <= 3; ++k) {
            k_spmm<20><<<nb((long long)N * 20), wg, 0, stream>>>(rowptr, emeta, hcur, hnext, N);
            k_matmul_acc<5><<<nb((long long)N * 128), wg, 0, stream>>>(hnext, W0 + k * 5 * 32, bufC, N, 0);
            float* tmp = hcur; hcur = hnext; hnext = tmp;
        }
        k_tanh_bias<<<nb((long long)N * 128), wg, 0, stream>>>(bufC, b0, bufA, nullptr, N);
    }

    // ---- layers 1 and 2: F=32 -> 32, fused hop+matmul ----
    dim3 nb8((unsigned)((N + 7) / 8));
    for (int layer = 1; layer <= 2; ++layer) {
        const float* W = (layer == 1) ? W1 : W2;
        const float* bb = (layer == 1) ? b1 : b2;
        float* hcur = bufA; float* hnext = bufB;
        k_matmul_acc<32><<<nb((long long)N * 128), wg, 0, stream>>>(hcur, W, bufC, N, 1);
        for (int k = 1; k <= 3; ++k) {
            if (k < 3)
                k_hop_fused<true><<<nb8, wg, 0, stream>>>(rowptr, emeta, hcur, hnext,
                                                          W + k * 32 * 32, bufC, N);
            else
                k_hop_fused<false><<<nb8, wg, 0, stream>>>(rowptr, emeta, hcur, nullptr,
                                                           W + k * 32 * 32, bufC, N);
            float* tmp = hcur; hcur = hnext; hnext = tmp;
        }
        k_tanh_bias<<<nb((long long)N * 128), wg, 0, stream>>>(bufC, bb, bufA,
                                                               (layer == 2) ? out_h : nullptr, N);
    }

    // ---- predictions ----
    k_pred<<<nb((long long)4 * N), wg, 0, stream>>>(bufA, Wr, br, out_pred, N);
}

// Round 4
// 658.782 us; speedup vs baseline: 2.3420x; 1.2234x over previous
//
#include <hip/hip_runtime.h>

#define WG 256

// ---------------- setup kernels ----------------

__global__ void k_zero2(int* __restrict__ a, int* __restrict__ b, int n) {
    int i = blockIdx.x * blockDim.x + threadIdx.x;
    if (i < n) { a[i] = 0; b[i] = 0; }
}

__global__ void k_count(const int* __restrict__ dst, int* __restrict__ deg, int E) {
    int e = blockIdx.x * blockDim.x + threadIdx.x;
    if (e < E) atomicAdd(&deg[dst[e]], 1);
}

__global__ void k_dis(const int* __restrict__ deg, float* __restrict__ dis, int N) {
    int n = blockIdx.x * blockDim.x + threadIdx.x;
    if (n < N) {
        int d = deg[n];
        dis[n] = (d > 0) ? rsqrtf((float)d) : 0.0f;
    }
}

// ---- hierarchical scan: blk (per-1024 exclusive) -> top (block sums) -> add ----
__global__ __launch_bounds__(1024) void k_scan_blk(const int* __restrict__ deg,
                                                   int* __restrict__ rowptr,
                                                   int* __restrict__ bsum, int N) {
    __shared__ int s[1024];
    int t = threadIdx.x;
    int gid = blockIdx.x * 1024 + t;
    int v = (gid < N) ? deg[gid] : 0;
    s[t] = v;
    __syncthreads();
    for (int off = 1; off < 1024; off <<= 1) {
        int u = (t >= off) ? s[t - off] : 0;
        __syncthreads();
        s[t] += u;
        __syncthreads();
    }
    if (gid < N) rowptr[gid] = s[t] - v;        // block-local exclusive
    if (t == 1023) bsum[blockIdx.x] = s[1023];  // block total
}

__global__ void k_scan_top(int* __restrict__ bsum, int* __restrict__ rowptr_last, int nb) {
    if (threadIdx.x == 0 && blockIdx.x == 0) {
        int run = 0;
        for (int i = 0; i < nb; ++i) { int v = bsum[i]; bsum[i] = run; run += v; }
        *rowptr_last = run;
    }
}

__global__ void k_scan_add(int* __restrict__ rowptr, const int* __restrict__ bsum, int N) {
    int gid = blockIdx.x * blockDim.x + threadIdx.x;
    if (gid < N) rowptr[gid] += bsum[gid >> 10];
}

// emeta[slot] = (src, w) packed as int2
__global__ void k_scatter(const int* __restrict__ src, const int* __restrict__ dst,
                          const int* __restrict__ rowptr, int* __restrict__ fill,
                          const float* __restrict__ dis,
                          int2* __restrict__ emeta, int E) {
    int e = blockIdx.x * blockDim.x + threadIdx.x;
    if (e >= E) return;
    int d = dst[e], s = src[e];
    int slot = rowptr[d] + atomicAdd(&fill[d], 1);
    emeta[slot] = make_int2(s, __float_as_int(dis[s] * dis[d]));
}

// X (B,WIN,N) f32 -> h0 [n][w][b] f32  (float4 per (n,w))
__global__ void k_xpose(const float* __restrict__ X, float* __restrict__ h0, int N) {
    long long tid = (long long)blockIdx.x * blockDim.x + threadIdx.x;
    if (tid >= (long long)N * 20) return;
    int n = (int)(tid / 20), r = (int)(tid % 20);
    int b = r & 3, w = r >> 2;
    h0[tid] = X[(size_t)(b * 5 + w) * N + n];
}

// ---------------- layer-0 propagation: float4 over [n][w][4b], 5 lanes/node ----------------
__global__ void k_spmm20(const int* __restrict__ rowptr, const int2* __restrict__ emeta,
                         const float* __restrict__ hin, float* __restrict__ hout, int N) {
    long long tid = (long long)blockIdx.x * blockDim.x + threadIdx.x;
    if (tid >= (long long)N * 5) return;
    int n = (int)(tid / 5), w = (int)(tid % 5);
    const float4* hin4 = (const float4*)hin;
    float ax = 0.f, ay = 0.f, az = 0.f, aw = 0.f;
    float bx = 0.f, by = 0.f, bz = 0.f, bw = 0.f;
    int j = rowptr[n], j1 = rowptr[n + 1];
    for (; j + 1 < j1; j += 2) {
        int2 m0 = emeta[j], m1 = emeta[j + 1];
        float4 g0 = hin4[(size_t)m0.x * 5 + w];
        float4 g1 = hin4[(size_t)m1.x * 5 + w];
        float w0 = __int_as_float(m0.y), w1 = __int_as_float(m1.y);
        ax += w0 * g0.x; ay += w0 * g0.y; az += w0 * g0.z; aw += w0 * g0.w;
        bx += w1 * g1.x; by += w1 * g1.y; bz += w1 * g1.z; bw += w1 * g1.w;
    }
    if (j < j1) {
        int2 m = emeta[j];
        float4 g = hin4[(size_t)m.x * 5 + w];
        float wt = __int_as_float(m.y);
        ax += wt * g.x; ay += wt * g.y; az += wt * g.z; aw += wt * g.w;
    }
    float4 o; o.x = ax + bx; o.y = ay + by; o.z = az + bz; o.w = aw + bw;
    ((float4*)hout)[(size_t)n * 5 + w] = o;
}

// acc[n][b][o] (+)= sum_w h[n][w][b] * W[w][o]   (one 5x32 k-slice)
__global__ void k_mm5(const float* __restrict__ h, const float* __restrict__ W,
                      float* __restrict__ acc, int N, int first) {
    __shared__ float w[5 * 32];
    int t = threadIdx.x;
    if (t < 160) w[t] = W[t];
    __syncthreads();
    long long tid = (long long)blockIdx.x * WG + t;
    int node = (int)(tid >> 7);
    if (node >= N) return;
    int b = ((int)tid >> 5) & 3, o = (int)tid & 31;
    const float* hp = h + (size_t)node * 20 + b;
    float a = first ? 0.0f : acc[tid];
#pragma unroll
    for (int f = 0; f < 5; ++f) a += hp[f * 4] * w[f * 32 + o];
    acc[tid] = a;
}

// layer-0 tail: acc += h20*W0[3]; v=tanh(acc+b0); hout=v; acc_out = v*Wnext (k=0 of layer 1)
__global__ __launch_bounds__(256) void k_mm5_final(const float* __restrict__ h20,
                                                   const float* __restrict__ W03,
                                                   const float* __restrict__ bias,
                                                   const float* __restrict__ acc_in,
                                                   float* __restrict__ hout,
                                                   const float* __restrict__ Wnext,
                                                   float* __restrict__ acc_out, int N) {
    __shared__ float4 wn4[256];
    __shared__ float4 w03[40];
    __shared__ float  hs[8 * 132];
    int t = threadIdx.x;
    wn4[t] = ((const float4*)Wnext)[t];
    if (t < 40) w03[t] = ((const float4*)W03)[t];
    __syncthreads();
    int nl = t >> 5, lane = t & 31, b = lane >> 3, q = lane & 7;
    int n = blockIdx.x * 8 + nl;
    bool valid = (n < N);
    float4 v4 = make_float4(0.f, 0.f, 0.f, 0.f);
    if (valid) {
        float4 a = ((const float4*)acc_in)[(size_t)n * 32 + lane];
#pragma unroll
        for (int w = 0; w < 5; ++w) {
            float hv = h20[(size_t)n * 20 + w * 4 + b];
            float4 wv = w03[w * 8 + q];
            a.x += hv * wv.x; a.y += hv * wv.y; a.z += hv * wv.z; a.w += hv * wv.w;
        }
        float4 b4 = ((const float4*)bias)[q];
        v4.x = tanhf(a.x + b4.x); v4.y = tanhf(a.y + b4.y);
        v4.z = tanhf(a.z + b4.z); v4.w = tanhf(a.w + b4.w);
        ((float4*)hout)[(size_t)n * 32 + lane] = v4;
    }
    float* hrow = &hs[nl * 132 + b * 33 + q * 4];
    hrow[0] = v4.x; hrow[1] = v4.y; hrow[2] = v4.z; hrow[3] = v4.w;
    __syncthreads();
    float sx = 0.f, sy = 0.f, sz = 0.f, sw = 0.f;
    const float* hb = &hs[nl * 132 + b * 33];
#pragma unroll
    for (int f = 0; f < 32; ++f) {
        float hv = hb[f];
        float4 wv = wn4[f * 8 + q];
        sx += hv * wv.x; sy += hv * wv.y; sz += hv * wv.z; sw += hv * wv.w;
    }
    if (valid) {
        float4 o; o.x = sx; o.y = sy; o.z = sz; o.w = sw;
        ((float4*)acc_out)[(size_t)n * 32 + lane] = o;
    }
}

// ---------------- fused mid hop (F=32): hnext = A*hin ; acc += hnext * Wk ----------------
__global__ __launch_bounds__(256) void k_hop_fused(const int* __restrict__ rowptr,
                                                   const int2* __restrict__ emeta,
                                                   const float* __restrict__ hin,
                                                   float* __restrict__ hnext,
                                                   const float* __restrict__ Wk,
                                                   float* __restrict__ acc, int N) {
    __shared__ float4 ws4[256];
    __shared__ float  hs[8 * 132];

    int t = threadIdx.x;
    ws4[t] = ((const float4*)Wk)[t];

    int nl = t >> 5, lane = t & 31;
    int n = blockIdx.x * 8 + nl;
    bool valid = (n < N);

    float ax = 0.f, ay = 0.f, az = 0.f, aw = 0.f;
    float bx = 0.f, by = 0.f, bz = 0.f, bw = 0.f;
    const float4* hin4 = (const float4*)hin;

    if (valid) {
        int j = rowptr[n], j1 = rowptr[n + 1];
        for (; j + 3 < j1; j += 4) {
            int2 m0 = emeta[j], m1 = emeta[j + 1], m2 = emeta[j + 2], m3 = emeta[j + 3];
            float4 g0 = hin4[(size_t)m0.x * 32 + lane];
            float4 g1 = hin4[(size_t)m1.x * 32 + lane];
            float4 g2 = hin4[(size_t)m2.x * 32 + lane];
            float4 g3 = hin4[(size_t)m3.x * 32 + lane];
            float w0 = __int_as_float(m0.y), w1 = __int_as_float(m1.y);
            float w2 = __int_as_float(m2.y), w3 = __int_as_float(m3.y);
            ax += w0 * g0.x; ay += w0 * g0.y; az += w0 * g0.z; aw += w0 * g0.w;
            bx += w1 * g1.x; by += w1 * g1.y; bz += w1 * g1.z; bw += w1 * g1.w;
            ax += w2 * g2.x; ay += w2 * g2.y; az += w2 * g2.z; aw += w2 * g2.w;
            bx += w3 * g3.x; by += w3 * g3.y; bz += w3 * g3.z; bw += w3 * g3.w;
        }
        for (; j < j1; ++j) {
            int2 m = emeta[j];
            float4 g = hin4[(size_t)m.x * 32 + lane];
            float w = __int_as_float(m.y);
            ax += w * g.x; ay += w * g.y; az += w * g.z; aw += w * g.w;
        }
        ax += bx; ay += by; az += bz; aw += bw;
        float4 o; o.x = ax; o.y = ay; o.z = az; o.w = aw;
        ((float4*)hnext)[(size_t)n * 32 + lane] = o;
    }

    int b = lane >> 3, q = lane & 7;
    float* hrow = &hs[nl * 132 + b * 33 + q * 4];
    hrow[0] = ax; hrow[1] = ay; hrow[2] = az; hrow[3] = aw;
    __syncthreads();
    if (!valid) return;

    float rx = 0.f, ry = 0.f, rz = 0.f, rw = 0.f;
    const float* hb = &hs[nl * 132 + b * 33];
#pragma unroll
    for (int f = 0; f < 32; ++f) {
        float hv = hb[f];
        float4 wv = ws4[f * 8 + q];
        rx += hv * wv.x; ry += hv * wv.y; rz += hv * wv.z; rw += hv * wv.w;
    }
    float4* accp = (float4*)acc + (size_t)n * 32 + lane;
    float4 cur = *accp;
    cur.x += rx; cur.y += ry; cur.z += rz; cur.w += rw;
    *accp = cur;
}

// ---------------- last hop of a layer, fused epilogue ----------------
// MODE 1: v=tanh(acc+h'*Wk+b); hout=v; acc_out = v*Wnext (next layer k=0)
// MODE 2: v=tanh(acc+h'*Wk+b); out_h=v (b*N+n layout); pred = v.Wr + br (shfl reduce)
template <int MODE>
__global__ __launch_bounds__(256) void k_hop_last(const int* __restrict__ rowptr,
                                                  const int2* __restrict__ emeta,
                                                  const float* __restrict__ hin,
                                                  const float* __restrict__ Wk,
                                                  const float* __restrict__ acc_in,
                                                  const float* __restrict__ bias,
                                                  float* __restrict__ hout,
                                                  const float* __restrict__ Wnext,
                                                  float* __restrict__ acc_out,
                                                  float* __restrict__ out_h,
                                                  const float* __restrict__ Wr,
                                                  const float* __restrict__ br,
                                                  float* __restrict__ pred, int N) {
    __shared__ float4 ws4[256];
    __shared__ float4 wn4[256];
    __shared__ float  hs[8 * 132];

    int t = threadIdx.x;
    ws4[t] = ((const float4*)Wk)[t];
    if (MODE == 1) wn4[t] = ((const float4*)Wnext)[t];

    int nl = t >> 5, lane = t & 31;
    int n = blockIdx.x * 8 + nl;
    bool valid = (n < N);
    int b = lane >> 3, q = lane & 7;

    float ax = 0.f, ay = 0.f, az = 0.f, aw = 0.f;
    float bx = 0.f, by = 0.f, bz = 0.f, bw = 0.f;
    const float4* hin4 = (const float4*)hin;

    if (valid) {
        int j = rowptr[n], j1 = rowptr[n + 1];
        for (; j + 3 < j1; j += 4) {
            int2 m0 = emeta[j], m1 = emeta[j + 1], m2 = emeta[j + 2], m3 = emeta[j + 3];
            float4 g0 = hin4[(size_t)m0.x * 32 + lane];
            float4 g1 = hin4[(size_t)m1.x * 32 + lane];
            float4 g2 = hin4[(size_t)m2.x * 32 + lane];
            float4 g3 = hin4[(size_t)m3.x * 32 + lane];
            float w0 = __int_as_float(m0.y), w1 = __int_as_float(m1.y);
            float w2 = __int_as_float(m2.y), w3 = __int_as_float(m3.y);
            ax += w0 * g0.x; ay += w0 * g0.y; az += w0 * g0.z; aw += w0 * g0.w;
            bx += w1 * g1.x; by += w1 * g1.y; bz += w1 * g1.z; bw += w1 * g1.w;
            ax += w2 * g2.x; ay += w2 * g2.y; az += w2 * g2.z; aw += w2 * g2.w;
            bx += w3 * g3.x; by += w3 * g3.y; bz += w3 * g3.z; bw += w3 * g3.w;
        }
        for (; j < j1; ++j) {
            int2 m = emeta[j];
            float4 g = hin4[(size_t)m.x * 32 + lane];
            float w = __int_as_float(m.y);
            ax += w * g.x; ay += w * g.y; az += w * g.z; aw += w * g.w;
        }
        ax += bx; ay += by; az += bz; aw += bw;
    }

    float* hrow = &hs[nl * 132 + b * 33 + q * 4];
    hrow[0] = ax; hrow[1] = ay; hrow[2] = az; hrow[3] = aw;
    __syncthreads();

    float rx = 0.f, ry = 0.f, rz = 0.f, rw = 0.f;
    const float* hb = &hs[nl * 132 + b * 33];
#pragma unroll
    for (int f = 0; f < 32; ++f) {
        float hv = hb[f];
        float4 wv = ws4[f * 8 + q];
        rx += hv * wv.x; ry += hv * wv.y; rz += hv * wv.z; rw += hv * wv.w;
    }

    float4 v4 = make_float4(0.f, 0.f, 0.f, 0.f);
    if (valid) {
        float4 a = ((const float4*)acc_in)[(size_t)n * 32 + lane];
        float4 b4 = ((const float4*)bias)[q];
        v4.x = tanhf(a.x + rx + b4.x);
        v4.y = tanhf(a.y + ry + b4.y);
        v4.z = tanhf(a.z + rz + b4.z);
        v4.w = tanhf(a.w + rw + b4.w);
    }

    if (MODE == 1) {
        if (valid) ((float4*)hout)[(size_t)n * 32 + lane] = v4;
        __syncthreads();            // all reads of hs (h') complete
        hrow[0] = v4.x; hrow[1] = v4.y; hrow[2] = v4.z; hrow[3] = v4.w;
        __syncthreads();
        float sx = 0.f, sy = 0.f, sz = 0.f, sw = 0.f;
#pragma unroll
        for (int f = 0; f < 32; ++f) {
            float hv = hb[f];
            float4 wv = wn4[f * 8 + q];
            sx += hv * wv.x; sy += hv * wv.y; sz += hv * wv.z; sw += hv * wv.w;
        }
        if (valid) {
            float4 o; o.x = sx; o.y = sy; o.z = sz; o.w = sw;
            ((float4*)acc_out)[(size_t)n * 32 + lane] = o;
        }
    } else {
        if (valid) {
            ((float4*)out_h)[((size_t)b * N + n) * 8 + q] = v4;
            float4 wr4 = ((const float4*)Wr)[q];
            float p = v4.x * wr4.x + v4.y * wr4.y + v4.z * wr4.z + v4.w * wr4.w;
            p += __shfl_xor(p, 1);
            p += __shfl_xor(p, 2);
            p += __shfl_xor(p, 4);
            if (q == 0) pred[(size_t)b * N + n] = p + br[0];
        }
    }
}

// ---------------- driver ----------------

extern "C" void kernel_launch(void* const* d_in, const int* in_sizes, int n_in,
                              void* d_out, int out_size, void* d_ws, size_t ws_size,
                              hipStream_t stream) {
    const float* X  = (const float*)d_in[0];
    const int*   ei = (const int*)d_in[1];
    const float* W0 = (const float*)d_in[2];
    const float* b0 = (const float*)d_in[3];
    const float* W1 = (const float*)d_in[4];
    const float* b1 = (const float*)d_in[5];
    const float* W2 = (const float*)d_in[6];
    const float* b2 = (const float*)d_in[7];
    const float* Wr = (const float*)d_in[8];
    const float* br = (const float*)d_in[9];

    const int N = in_sizes[0] / 20;
    const int E = in_sizes[1] / 2;
    const int* src = ei;
    const int* dst = ei + E;
    const int nscan = (N + 1023) / 1024;

    char* ws = (char*)d_ws;
    size_t off = 0;
    auto take = [&](size_t bytes) -> char* {
        char* p = ws + off;
        off = (off + bytes + 255) & ~(size_t)255;
        return p;
    };
    int*   deg    = (int*)  take((size_t)N * 4);
    int*   fill   = (int*)  take((size_t)N * 4);
    int*   rowptr = (int*)  take(((size_t)N + 1) * 4);
    float* dis    = (float*)take((size_t)N * 4);
    int*   bsum   = (int*)  take((size_t)(nscan + 1) * 4);
    int2*  emeta  = (int2*) take((size_t)E * 8);
    float* acc    = (float*)take((size_t)N * 128 * 4);
    float* h32a   = (float*)take((size_t)N * 128 * 4);
    float* h32b   = (float*)take((size_t)N * 128 * 4);
    if (ws_size < off) return;
    // layer-0 ping-pong buffers alias h32b (dead by the time h32b is first written)
    float* h20a = h32b;
    float* h20b = h32b + (size_t)N * 20;

    dim3 wg(WG);
    auto nb = [](long long total) { return dim3((unsigned)((total + WG - 1) / WG)); };
    dim3 nb8((unsigned)((N + 7) / 8));

    // ---- graph/normalization setup ----
    k_zero2<<<nb(N), wg, 0, stream>>>(deg, fill, N);
    k_count<<<nb(E), wg, 0, stream>>>(dst, deg, E);
    k_dis<<<nb(N), wg, 0, stream>>>(deg, dis, N);
    k_scan_blk<<<dim3(nscan), dim3(1024), 0, stream>>>(deg, rowptr, bsum, N);
    k_scan_top<<<dim3(1), dim3(64), 0, stream>>>(bsum, rowptr + N, nscan);
    k_scan_add<<<nb(N), wg, 0, stream>>>(rowptr, bsum, N);
    k_scatter<<<nb(E), wg, 0, stream>>>(src, dst, rowptr, fill, dis, emeta, E);

    // ---- h0 = X^T -> [n][w][4b] ----
    k_xpose<<<nb((long long)N * 20), wg, 0, stream>>>(X, h20a, N);

    float* out_pred = (float*)d_out;
    float* out_h    = (float*)d_out + (size_t)4 * N;

    // ---- layer 0 (5 -> 32) ----
    k_mm5<<<nb((long long)N * 128), wg, 0, stream>>>(h20a, W0, acc, N, 1);
    k_spmm20<<<nb((long long)N * 5), wg, 0, stream>>>(rowptr, emeta, h20a, h20b, N);
    k_mm5<<<nb((long long)N * 128), wg, 0, stream>>>(h20b, W0 + 160, acc, N, 0);
    k_spmm20<<<nb((long long)N * 5), wg, 0, stream>>>(rowptr, emeta, h20b, h20a, N);
    k_mm5<<<nb((long long)N * 128), wg, 0, stream>>>(h20a, W0 + 320, acc, N, 0);
    k_spmm20<<<nb((long long)N * 5), wg, 0, stream>>>(rowptr, emeta, h20a, h20b, N);
    k_mm5_final<<<nb8, wg, 0, stream>>>(h20b, W0 + 480, b0, acc, h32a, W1, acc, N);

    // ---- layer 1 (32 -> 32) ----
    k_hop_fused<<<nb8, wg, 0, stream>>>(rowptr, emeta, h32a, h32b, W1 + 1024, acc, N);
    k_hop_fused<<<nb8, wg, 0, stream>>>(rowptr, emeta, h32b, h32a, W1 + 2048, acc, N);
    k_hop_last<1><<<nb8, wg, 0, stream>>>(rowptr, emeta, h32a, W1 + 3072, acc, b1,
                                          h32b, W2, acc, nullptr, nullptr, nullptr, nullptr, N);

    // ---- layer 2 (32 -> 32) ----
    k_hop_fused<<<nb8, wg, 0, stream>>>(rowptr, emeta, h32b, h32a, W2 + 1024, acc, N);
    k_hop_fused<<<nb8, wg, 0, stream>>>(rowptr, emeta, h32a, h32b, W2 + 2048, acc, N);
    k_hop_last<2><<<nb8, wg, 0, stream>>>(rowptr, emeta, h32b, W2 + 3072, acc, b2,
                                          nullptr, nullptr, nullptr, out_h, Wr, br, out_pred, N);
}

// Round 5
// 559.577 us; speedup vs baseline: 2.7573x; 1.1773x over previous
//
#include <hip/hip_runtime.h>
#include <hip/hip_fp16.h>

#define WG 256

// ---- fp16 pack/unpack helpers (4 channels <-> uint2) ----
__device__ __forceinline__ float4 h4_to_f4(uint2 u) {
    union { unsigned int x; __half2 h; } a, b;
    a.x = u.x; b.x = u.y;
    float2 f0 = __half22float2(a.h);
    float2 f1 = __half22float2(b.h);
    return make_float4(f0.x, f0.y, f1.x, f1.y);
}
__device__ __forceinline__ uint2 f4_to_h4(float4 v) {
    union { unsigned int x; __half2 h; } a, b;
    a.h = __floats2half2_rn(v.x, v.y);
    b.h = __floats2half2_rn(v.z, v.w);
    return make_uint2(a.x, b.x);
}

// ---------------- setup kernels ----------------

__global__ void k_zero2(int* __restrict__ a, int* __restrict__ b, int n) {
    int i = blockIdx.x * blockDim.x + threadIdx.x;
    if (i < n) { a[i] = 0; b[i] = 0; }
}

__global__ void k_count(const int* __restrict__ dst, int* __restrict__ deg, int E) {
    int e = blockIdx.x * blockDim.x + threadIdx.x;
    if (e < E) atomicAdd(&deg[dst[e]], 1);
}

__global__ void k_dis(const int* __restrict__ deg, float* __restrict__ dis, int N) {
    int n = blockIdx.x * blockDim.x + threadIdx.x;
    if (n < N) {
        int d = deg[n];
        dis[n] = (d > 0) ? rsqrtf((float)d) : 0.0f;
    }
}

// ---- hierarchical scan ----
__global__ __launch_bounds__(1024) void k_scan_blk(const int* __restrict__ deg,
                                                   int* __restrict__ rowptr,
                                                   int* __restrict__ bsum, int N) {
    __shared__ int s[1024];
    int t = threadIdx.x;
    int gid = blockIdx.x * 1024 + t;
    int v = (gid < N) ? deg[gid] : 0;
    s[t] = v;
    __syncthreads();
    for (int off = 1; off < 1024; off <<= 1) {
        int u = (t >= off) ? s[t - off] : 0;
        __syncthreads();
        s[t] += u;
        __syncthreads();
    }
    if (gid < N) rowptr[gid] = s[t] - v;
    if (t == 1023) bsum[blockIdx.x] = s[1023];
}

__global__ void k_scan_top(int* __restrict__ bsum, int* __restrict__ rowptr_last, int nb) {
    if (threadIdx.x == 0 && blockIdx.x == 0) {
        int run = 0;
        for (int i = 0; i < nb; ++i) { int v = bsum[i]; bsum[i] = run; run += v; }
        *rowptr_last = run;
    }
}

__global__ void k_scan_add(int* __restrict__ rowptr, const int* __restrict__ bsum, int N) {
    int gid = blockIdx.x * blockDim.x + threadIdx.x;
    if (gid < N) rowptr[gid] += bsum[gid >> 10];
}

__global__ void k_scatter(const int* __restrict__ src, const int* __restrict__ dst,
                          const int* __restrict__ rowptr, int* __restrict__ fill,
                          const float* __restrict__ dis,
                          int2* __restrict__ emeta, int E) {
    int e = blockIdx.x * blockDim.x + threadIdx.x;
    if (e >= E) return;
    int d = dst[e], s = src[e];
    int slot = rowptr[d] + atomicAdd(&fill[d], 1);
    emeta[slot] = make_int2(s, __float_as_int(dis[s] * dis[d]));
}

// X (B,WIN,N) f32 -> h0 [n][w][b] f32
__global__ void k_xpose(const float* __restrict__ X, float* __restrict__ h0, int N) {
    long long tid = (long long)blockIdx.x * blockDim.x + threadIdx.x;
    if (tid >= (long long)N * 20) return;
    int n = (int)(tid / 20), r = (int)(tid % 20);
    int b = r & 3, w = r >> 2;
    h0[tid] = X[(size_t)(b * 5 + w) * N + n];
}

// ---------------- layer-0 propagation (f32, table is only 4 MB) ----------------
__global__ void k_spmm20(const int* __restrict__ rowptr, const int2* __restrict__ emeta,
                         const float* __restrict__ hin, float* __restrict__ hout, int N) {
    long long tid = (long long)blockIdx.x * blockDim.x + threadIdx.x;
    if (tid >= (long long)N * 5) return;
    int n = (int)(tid / 5), w = (int)(tid % 5);
    const float4* hin4 = (const float4*)hin;
    float ax = 0.f, ay = 0.f, az = 0.f, aw = 0.f;
    float bx = 0.f, by = 0.f, bz = 0.f, bw = 0.f;
    int j = rowptr[n], j1 = rowptr[n + 1];
    for (; j + 1 < j1; j += 2) {
        int2 m0 = emeta[j], m1 = emeta[j + 1];
        float4 g0 = hin4[(size_t)m0.x * 5 + w];
        float4 g1 = hin4[(size_t)m1.x * 5 + w];
        float w0 = __int_as_float(m0.y), w1 = __int_as_float(m1.y);
        ax += w0 * g0.x; ay += w0 * g0.y; az += w0 * g0.z; aw += w0 * g0.w;
        bx += w1 * g1.x; by += w1 * g1.y; bz += w1 * g1.z; bw += w1 * g1.w;
    }
    if (j < j1) {
        int2 m = emeta[j];
        float4 g = hin4[(size_t)m.x * 5 + w];
        float wt = __int_as_float(m.y);
        ax += wt * g.x; ay += wt * g.y; az += wt * g.z; aw += wt * g.w;
    }
    float4 o; o.x = ax + bx; o.y = ay + by; o.z = az + bz; o.w = aw + bw;
    ((float4*)hout)[(size_t)n * 5 + w] = o;
}

// acc[n][b][o] (+)= sum_w h[n][w][b] * W[w][o]
__global__ void k_mm5(const float* __restrict__ h, const float* __restrict__ W,
                      float* __restrict__ acc, int N, int first) {
    __shared__ float w[5 * 32];
    int t = threadIdx.x;
    if (t < 160) w[t] = W[t];
    __syncthreads();
    long long tid = (long long)blockIdx.x * WG + t;
    int node = (int)(tid >> 7);
    if (node >= N) return;
    int b = ((int)tid >> 5) & 3, o = (int)tid & 31;
    const float* hp = h + (size_t)node * 20 + b;
    float a = first ? 0.0f : acc[tid];
#pragma unroll
    for (int f = 0; f < 5; ++f) a += hp[f * 4] * w[f * 32 + o];
    acc[tid] = a;
}

// layer-0 tail: acc += h20*W0[3]; v=tanh(acc+b0); hout(fp16)=v; acc_out = v*Wnext[k=0]
__global__ __launch_bounds__(256) void k_mm5_final(const float* __restrict__ h20,
                                                   const float* __restrict__ W03,
                                                   const float* __restrict__ bias,
                                                   const float* __restrict__ acc_in,
                                                   uint2* __restrict__ hout,
                                                   const float* __restrict__ Wnext,
                                                   float* __restrict__ acc_out, int N) {
    __shared__ float4 wn4[256];
    __shared__ float4 w03[40];
    __shared__ float  hs[8 * 132];
    int t = threadIdx.x;
    wn4[t] = ((const float4*)Wnext)[t];
    if (t < 40) w03[t] = ((const float4*)W03)[t];
    __syncthreads();
    int nl = t >> 5, lane = t & 31, b = lane >> 3, q = lane & 7;
    int n = blockIdx.x * 8 + nl;
    bool valid = (n < N);
    float4 v4 = make_float4(0.f, 0.f, 0.f, 0.f);
    if (valid) {
        float4 a = ((const float4*)acc_in)[(size_t)n * 32 + lane];
#pragma unroll
        for (int w = 0; w < 5; ++w) {
            float hv = h20[(size_t)n * 20 + w * 4 + b];
            float4 wv = w03[w * 8 + q];
            a.x += hv * wv.x; a.y += hv * wv.y; a.z += hv * wv.z; a.w += hv * wv.w;
        }
        float4 b4 = ((const float4*)bias)[q];
        v4.x = tanhf(a.x + b4.x); v4.y = tanhf(a.y + b4.y);
        v4.z = tanhf(a.z + b4.z); v4.w = tanhf(a.w + b4.w);
        hout[(size_t)n * 32 + lane] = f4_to_h4(v4);
    }
    float* hrow = &hs[nl * 132 + b * 33 + q * 4];
    hrow[0] = v4.x; hrow[1] = v4.y; hrow[2] = v4.z; hrow[3] = v4.w;
    __syncthreads();
    float sx = 0.f, sy = 0.f, sz = 0.f, sw = 0.f;
    const float* hb = &hs[nl * 132 + b * 33];
#pragma unroll
    for (int f = 0; f < 32; ++f) {
        float hv = hb[f];
        float4 wv = wn4[f * 8 + q];
        sx += hv * wv.x; sy += hv * wv.y; sz += hv * wv.z; sw += hv * wv.w;
    }
    if (valid) {
        float4 o; o.x = sx; o.y = sy; o.z = sz; o.w = sw;
        ((float4*)acc_out)[(size_t)n * 32 + lane] = o;
    }
}

// ---------------- fused mid hop (fp16 in/out): hnext = A*hin ; acc += hnext * Wk ----------------
__global__ __launch_bounds__(256) void k_hop_fused(const int* __restrict__ rowptr,
                                                   const int2* __restrict__ emeta,
                                                   const uint2* __restrict__ hin,
                                                   uint2* __restrict__ hnext,
                                                   const float* __restrict__ Wk,
                                                   float* __restrict__ acc, int N) {
    __shared__ float4 ws4[256];
    __shared__ float  hs[8 * 132];

    int t = threadIdx.x;
    ws4[t] = ((const float4*)Wk)[t];

    int nl = t >> 5, lane = t & 31;
    int n = blockIdx.x * 8 + nl;
    bool valid = (n < N);

    float ax = 0.f, ay = 0.f, az = 0.f, aw = 0.f;
    float bx = 0.f, by = 0.f, bz = 0.f, bw = 0.f;

    if (valid) {
        int j = rowptr[n], j1 = rowptr[n + 1];
        for (; j + 3 < j1; j += 4) {
            int2 m0 = emeta[j], m1 = emeta[j + 1], m2 = emeta[j + 2], m3 = emeta[j + 3];
            uint2 u0 = hin[(size_t)m0.x * 32 + lane];
            uint2 u1 = hin[(size_t)m1.x * 32 + lane];
            uint2 u2 = hin[(size_t)m2.x * 32 + lane];
            uint2 u3 = hin[(size_t)m3.x * 32 + lane];
            float4 g0 = h4_to_f4(u0), g1 = h4_to_f4(u1), g2 = h4_to_f4(u2), g3 = h4_to_f4(u3);
            float w0 = __int_as_float(m0.y), w1 = __int_as_float(m1.y);
            float w2 = __int_as_float(m2.y), w3 = __int_as_float(m3.y);
            ax += w0 * g0.x; ay += w0 * g0.y; az += w0 * g0.z; aw += w0 * g0.w;
            bx += w1 * g1.x; by += w1 * g1.y; bz += w1 * g1.z; bw += w1 * g1.w;
            ax += w2 * g2.x; ay += w2 * g2.y; az += w2 * g2.z; aw += w2 * g2.w;
            bx += w3 * g3.x; by += w3 * g3.y; bz += w3 * g3.z; bw += w3 * g3.w;
        }
        for (; j < j1; ++j) {
            int2 m = emeta[j];
            float4 g = h4_to_f4(hin[(size_t)m.x * 32 + lane]);
            float w = __int_as_float(m.y);
            ax += w * g.x; ay += w * g.y; az += w * g.z; aw += w * g.w;
        }
        ax += bx; ay += by; az += bz; aw += bw;
        float4 o; o.x = ax; o.y = ay; o.z = az; o.w = aw;
        hnext[(size_t)n * 32 + lane] = f4_to_h4(o);
    }

    int b = lane >> 3, q = lane & 7;
    float* hrow = &hs[nl * 132 + b * 33 + q * 4];
    hrow[0] = ax; hrow[1] = ay; hrow[2] = az; hrow[3] = aw;
    __syncthreads();
    if (!valid) return;

    float rx = 0.f, ry = 0.f, rz = 0.f, rw = 0.f;
    const float* hb = &hs[nl * 132 + b * 33];
#pragma unroll
    for (int f = 0; f < 32; ++f) {
        float hv = hb[f];
        float4 wv = ws4[f * 8 + q];
        rx += hv * wv.x; ry += hv * wv.y; rz += hv * wv.z; rw += hv * wv.w;
    }
    float4* accp = (float4*)acc + (size_t)n * 32 + lane;
    float4 cur = *accp;
    cur.x += rx; cur.y += ry; cur.z += rz; cur.w += rw;
    *accp = cur;
}

// ---------------- last hop of a layer, fused epilogue ----------------
// MODE 1: v=tanh(acc+h'*Wk+b); hout(fp16)=v; acc_out = v*Wnext (next layer k=0)
// MODE 2: v=tanh(acc+h'*Wk+b); out_h(f32)=v; pred = v.Wr + br
template <int MODE>
__global__ __launch_bounds__(256) void k_hop_last(const int* __restrict__ rowptr,
                                                  const int2* __restrict__ emeta,
                                                  const uint2* __restrict__ hin,
                                                  const float* __restrict__ Wk,
                                                  const float* __restrict__ acc_in,
                                                  const float* __restrict__ bias,
                                                  uint2* __restrict__ hout,
                                                  const float* __restrict__ Wnext,
                                                  float* __restrict__ acc_out,
                                                  float* __restrict__ out_h,
                                                  const float* __restrict__ Wr,
                                                  const float* __restrict__ br,
                                                  float* __restrict__ pred, int N) {
    __shared__ float4 ws4[256];
    __shared__ float4 wn4[256];
    __shared__ float  hs[8 * 132];

    int t = threadIdx.x;
    ws4[t] = ((const float4*)Wk)[t];
    if (MODE == 1) wn4[t] = ((const float4*)Wnext)[t];

    int nl = t >> 5, lane = t & 31;
    int n = blockIdx.x * 8 + nl;
    bool valid = (n < N);
    int b = lane >> 3, q = lane & 7;

    float ax = 0.f, ay = 0.f, az = 0.f, aw = 0.f;
    float bx = 0.f, by = 0.f, bz = 0.f, bw = 0.f;

    if (valid) {
        int j = rowptr[n], j1 = rowptr[n + 1];
        for (; j + 3 < j1; j += 4) {
            int2 m0 = emeta[j], m1 = emeta[j + 1], m2 = emeta[j + 2], m3 = emeta[j + 3];
            uint2 u0 = hin[(size_t)m0.x * 32 + lane];
            uint2 u1 = hin[(size_t)m1.x * 32 + lane];
            uint2 u2 = hin[(size_t)m2.x * 32 + lane];
            uint2 u3 = hin[(size_t)m3.x * 32 + lane];
            float4 g0 = h4_to_f4(u0), g1 = h4_to_f4(u1), g2 = h4_to_f4(u2), g3 = h4_to_f4(u3);
            float w0 = __int_as_float(m0.y), w1 = __int_as_float(m1.y);
            float w2 = __int_as_float(m2.y), w3 = __int_as_float(m3.y);
            ax += w0 * g0.x; ay += w0 * g0.y; az += w0 * g0.z; aw += w0 * g0.w;
            bx += w1 * g1.x; by += w1 * g1.y; bz += w1 * g1.z; bw += w1 * g1.w;
            ax += w2 * g2.x; ay += w2 * g2.y; az += w2 * g2.z; aw += w2 * g2.w;
            bx += w3 * g3.x; by += w3 * g3.y; bz += w3 * g3.z; bw += w3 * g3.w;
        }
        for (; j < j1; ++j) {
            int2 m = emeta[j];
            float4 g = h4_to_f4(hin[(size_t)m.x * 32 + lane]);
            float w = __int_as_float(m.y);
            ax += w * g.x; ay += w * g.y; az += w * g.z; aw += w * g.w;
        }
        ax += bx; ay += by; az += bz; aw += bw;
    }

    float* hrow = &hs[nl * 132 + b * 33 + q * 4];
    hrow[0] = ax; hrow[1] = ay; hrow[2] = az; hrow[3] = aw;
    __syncthreads();

    float rx = 0.f, ry = 0.f, rz = 0.f, rw = 0.f;
    const float* hb = &hs[nl * 132 + b * 33];
#pragma unroll
    for (int f = 0; f < 32; ++f) {
        float hv = hb[f];
        float4 wv = ws4[f * 8 + q];
        rx += hv * wv.x; ry += hv * wv.y; rz += hv * wv.z; rw += hv * wv.w;
    }

    float4 v4 = make_float4(0.f, 0.f, 0.f, 0.f);
    if (valid) {
        float4 a = ((const float4*)acc_in)[(size_t)n * 32 + lane];
        float4 b4 = ((const float4*)bias)[q];
        v4.x = tanhf(a.x + rx + b4.x);
        v4.y = tanhf(a.y + ry + b4.y);
        v4.z = tanhf(a.z + rz + b4.z);
        v4.w = tanhf(a.w + rw + b4.w);
    }

    if (MODE == 1) {
        if (valid) hout[(size_t)n * 32 + lane] = f4_to_h4(v4);
        __syncthreads();
        hrow[0] = v4.x; hrow[1] = v4.y; hrow[2] = v4.z; hrow[3] = v4.w;
        __syncthreads();
        float sx = 0.f, sy = 0.f, sz = 0.f, sw = 0.f;
#pragma unroll
        for (int f = 0; f < 32; ++f) {
            float hv = hb[f];
            float4 wv = wn4[f * 8 + q];
            sx += hv * wv.x; sy += hv * wv.y; sz += hv * wv.z; sw += hv * wv.w;
        }
        if (valid) {
            float4 o; o.x = sx; o.y = sy; o.z = sz; o.w = sw;
            ((float4*)acc_out)[(size_t)n * 32 + lane] = o;
        }
    } else {
        if (valid) {
            ((float4*)out_h)[((size_t)b * N + n) * 8 + q] = v4;
            float4 wr4 = ((const float4*)Wr)[q];
            float p = v4.x * wr4.x + v4.y * wr4.y + v4.z * wr4.z + v4.w * wr4.w;
            p += __shfl_xor(p, 1);
            p += __shfl_xor(p, 2);
            p += __shfl_xor(p, 4);
            if (q == 0) pred[(size_t)b * N + n] = p + br[0];
        }
    }
}

// ---------------- driver ----------------

extern "C" void kernel_launch(void* const* d_in, const int* in_sizes, int n_in,
                              void* d_out, int out_size, void* d_ws, size_t ws_size,
                              hipStream_t stream) {
    const float* X  = (const float*)d_in[0];
    const int*   ei = (const int*)d_in[1];
    const float* W0 = (const float*)d_in[2];
    const float* b0 = (const float*)d_in[3];
    const float* W1 = (const float*)d_in[4];
    const float* b1 = (const float*)d_in[5];
    const float* W2 = (const float*)d_in[6];
    const float* b2 = (const float*)d_in[7];
    const float* Wr = (const float*)d_in[8];
    const float* br = (const float*)d_in[9];

    const int N = in_sizes[0] / 20;
    const int E = in_sizes[1] / 2;
    const int* src = ei;
    const int* dst = ei + E;
    const int nscan = (N + 1023) / 1024;

    char* ws = (char*)d_ws;
    size_t off = 0;
    auto take = [&](size_t bytes) -> char* {
        char* p = ws + off;
        off = (off + bytes + 255) & ~(size_t)255;
        return p;
    };
    int*   deg    = (int*)  take((size_t)N * 4);
    int*   fill   = (int*)  take((size_t)N * 4);
    int*   rowptr = (int*)  take(((size_t)N + 1) * 4);
    float* dis    = (float*)take((size_t)N * 4);
    int*   bsum   = (int*)  take((size_t)(nscan + 1) * 4);
    int2*  emeta  = (int2*) take((size_t)E * 8);
    float* acc    = (float*)take((size_t)N * 128 * 4);
    uint2* h16a   = (uint2*)take((size_t)N * 128 * 2);   // fp16 node features
    uint2* h16b   = (uint2*)take((size_t)N * 128 * 2);
    float* h20a   = (float*)take((size_t)N * 20 * 4);    // layer-0 f32 ping-pong
    float* h20b   = (float*)take((size_t)N * 20 * 4);
    if (ws_size < off) return;

    dim3 wg(WG);
    auto nb = [](long long total) { return dim3((unsigned)((total + WG - 1) / WG)); };
    dim3 nb8((unsigned)((N + 7) / 8));

    // ---- graph/normalization setup ----
    k_zero2<<<nb(N), wg, 0, stream>>>(deg, fill, N);
    k_count<<<nb(E), wg, 0, stream>>>(dst, deg, E);
    k_dis<<<nb(N), wg, 0, stream>>>(deg, dis, N);
    k_scan_blk<<<dim3(nscan), dim3(1024), 0, stream>>>(deg, rowptr, bsum, N);
    k_scan_top<<<dim3(1), dim3(64), 0, stream>>>(bsum, rowptr + N, nscan);
    k_scan_add<<<nb(N), wg, 0, stream>>>(rowptr, bsum, N);
    k_scatter<<<nb(E), wg, 0, stream>>>(src, dst, rowptr, fill, dis, emeta, E);

    // ---- h0 = X^T -> [n][w][4b] ----
    k_xpose<<<nb((long long)N * 20), wg, 0, stream>>>(X, h20a, N);

    float* out_pred = (float*)d_out;
    float* out_h    = (float*)d_out + (size_t)4 * N;

    // ---- layer 0 (5 -> 32), f32 ----
    k_mm5<<<nb((long long)N * 128), wg, 0, stream>>>(h20a, W0, acc, N, 1);
    k_spmm20<<<nb((long long)N * 5), wg, 0, stream>>>(rowptr, emeta, h20a, h20b, N);
    k_mm5<<<nb((long long)N * 128), wg, 0, stream>>>(h20b, W0 + 160, acc, N, 0);
    k_spmm20<<<nb((long long)N * 5), wg, 0, stream>>>(rowptr, emeta, h20b, h20a, N);
    k_mm5<<<nb((long long)N * 128), wg, 0, stream>>>(h20a, W0 + 320, acc, N, 0);
    k_spmm20<<<nb((long long)N * 5), wg, 0, stream>>>(rowptr, emeta, h20a, h20b, N);
    k_mm5_final<<<nb8, wg, 0, stream>>>(h20b, W0 + 480, b0, acc, h16a, W1, acc, N);

    // ---- layer 1 (32 -> 32), fp16 node storage ----
    k_hop_fused<<<nb8, wg, 0, stream>>>(rowptr, emeta, h16a, h16b, W1 + 1024, acc, N);
    k_hop_fused<<<nb8, wg, 0, stream>>>(rowptr, emeta, h16b, h16a, W1 + 2048, acc, N);
    k_hop_last<1><<<nb8, wg, 0, stream>>>(rowptr, emeta, h16a, W1 + 3072, acc, b1,
                                          h16b, W2, acc, nullptr, nullptr, nullptr, nullptr, N);

    // ---- layer 2 (32 -> 32) ----
    k_hop_fused<<<nb8, wg, 0, stream>>>(rowptr, emeta, h16b, h16a, W2 + 1024, acc, N);
    k_hop_fused<<<nb8, wg, 0, stream>>>(rowptr, emeta, h16a, h16b, W2 + 2048, acc, N);
    k_hop_last<2><<<nb8, wg, 0, stream>>>(rowptr, emeta, h16b, W2 + 3072, acc, b2,
                                          nullptr, nullptr, nullptr, out_h, Wr, br, out_pred, N);
}